// Round 9
// baseline (275.283 us; speedup 1.0000x reference)
//
#include <hip/hip_runtime.h>
#include <hip/hip_bf16.h>

#define BATCH 32
#define WDIM 512
#define HDIM 512
#define CDIM 3
#define KPSF 32
#define NPRED (BATCH*WDIM*HDIM*CDIM)  // 25165824

#define TW 88            // x-window: 8 outputs at stride 8 (span 57) + 31 taps
#define NROW 64          // circular y-row buffer (63 live + 1 spare)
#define TE (TW*NROW)     // 5632 elements per channel plane
#define SOUT_OFF (CDIM*TE*2)            // 33792 B
#define LDS_BYTES (SOUT_OFF + 12288)    // 46080 B

typedef __bf16 bf16x8 __attribute__((ext_vector_type(8)));
typedef float floatx16 __attribute__((ext_vector_type(16)));
typedef float fx4 __attribute__((ext_vector_type(4)));

// Workgroup barrier that does NOT drain vmcnt: only LDS ordering is required;
// global loads/stores stay in flight across it.
__device__ __forceinline__ void barrier_lgkm() {
    __asm__ volatile("s_waitcnt lgkmcnt(0)\n\ts_barrier" ::: "memory");
}

// Pack psf[b,i,j,0,c] (fp32) into MFMA A-fragment order (bf16):
// dst[((c*32 + j)*2 + h)*64 + lane][t] = psf[b=lane&31][i=16h+8*(lane>>5)+t][j][c]
__global__ __launch_bounds__(64) void pack_psf(const float* __restrict__ psf,
                                               __bf16* __restrict__ dst,
                                               float* __restrict__ loss) {
    if (blockIdx.x == 0 && threadIdx.x == 0) *loss = 0.f;
    int idx = blockIdx.x;              // [0,192) = ((c*32 + j)*2 + h)
    int h = idx & 1;
    int j = (idx >> 1) & 31;
    int c = idx >> 6;
    int lane = threadIdx.x;
    int b = lane & 31;
    int q = lane >> 5;
    bf16x8 v;
#pragma unroll
    for (int t = 0; t < 8; ++t) {
        int i = 16*h + 8*q + t;
        v[t] = (__bf16)psf[((size_t)(b*KPSF + i)*KPSF + j)*CDIM + c];
    }
    *(bf16x8*)(dst + (size_t)(idx*64 + lane)*8) = v;
}

// Persistent-block design: grid = 256 (one fat block per CU), 192 threads =
// 3 waves (wave = channel). Each block owns one x-octet (8 outputs at stride
// 8) and processes 4 consecutive y-tiles with a rolling circular 64-row LDS
// image window (only 32 new rows staged per tile, prefetched a tile ahead).
// ~330 regs/wave (1 wave/SIMD) buys acc[8] + full obs prefetch + deep A ILP.
__global__ __launch_bounds__(192, 1) void conv_mfma(
    const float* __restrict__ obs,    // [B,W,H,C]
    const float* __restrict__ img,    // [W,H,C]
    const __bf16* __restrict__ psfA,  // packed A-frags (192 KB)
    float* __restrict__ out)          // [B,W,H,C] pred, then loss scalar
{
    __shared__ __align__(16) unsigned char smem[LDS_BYTES];
    __bf16* sim  = (__bf16*)smem;                   // 3 planes of [NROW][TW]
    float*  sOut = (float*)(smem + SOUT_OFF);       // 12288 B transpose buf

    const int tid  = threadIdx.x;
    const int lane = tid & 63;
    const int c    = tid >> 6;      // wave index = channel
    const int n    = lane & 31;     // MFMA n (y within tile)
    const int q    = lane >> 5;     // k-half selector

    const int bx = blockIdx.x;      // [0,256)
    const int r8 = bx & 7;          // x mod-8 class
    const int g  = (bx >> 3) & 7;   // 64-wide x group
    const int yq = bx >> 6;         // y quarter [0,4)
    const int x0 = g*64 + r8;       // outputs x0 + 8s, s=0..7
    const int Y0 = yq*128;          // y range [Y0, Y0+128)

    // ---- initial fill: rows [Y0-15, Y0+48) into circular slots (y&63) ----
    for (int e = tid; e < 88*189; e += 192) {
        int xl = e / 189;
        int r  = e - xl*189;
        int yl = r / 3;
        int cc = r - 3*yl;
        int x = x0 - 15 + xl;
        int y = Y0 - 15 + yl;
        float v = 0.f;
        if ((unsigned)x < WDIM && (unsigned)y < HDIM)
            v = img[((size_t)x*HDIM + y)*CDIM + cc];
        sim[cc*TE + ((y + 512) & 63)*TW + xl] = (__bf16)v;
    }

    const char* gA = (const char*)psfA + (size_t)c*65536 + (size_t)(lane*16);

    // epilogue base addresses (y-independent part)
    unsigned baseNoY[4];
#pragma unroll
    for (int k = 0; k < 4; ++k) {
        int f = tid + 192*k;                 // float4 index [0,768)
        int fb = f / 24;                     // batch
        int r4 = (f - fb*24) * 4;            // offset in 96-float (y,c) run
        baseNoY[k] = (unsigned)fb*(WDIM*HDIM*CDIM) + (unsigned)x0*(HDIM*CDIM) + r4;
    }

    float ls = 0.f;
    fx4 rl[11];                              // rolling-stage prefetch regs

#pragma unroll 1
    for (int tt = 0; tt < 4; ++tt) {
        const int Y = Y0 + 32*tt;

        // ---- scatter the pre-loaded roll (rows [Y+16, Y+48)) ----
        if (tt > 0) {
            const int y0r = Y + 16;
#pragma unroll
            for (int i = 0; i < 11; ++i) {
                int f = tid + 192*i;
                int col = f / 24;
                int v4  = f - col*24;
#pragma unroll
                for (int u = 0; u < 4; ++u) {
                    int dd = 4*v4 + u;
                    int yl = dd / 3;
                    int cc = dd - 3*yl;
                    int y  = y0r + yl;
                    float val = (y < HDIM) ? rl[i][u] : 0.f;
                    sim[cc*TE + (y & 63)*TW + col] = (__bf16)val;
                }
            }
        }
        barrier_lgkm();     // sim tile ready for all waves

        // ---- issue next roll's loads (consumed next tile: full-main cover) --
        if (tt < 3) {
            const int y0n = Y + 48;          // rows [Y+48, Y+80)
#pragma unroll
            for (int i = 0; i < 11; ++i) {
                int f = tid + 192*i;
                int col = f / 24;
                int v4  = f - col*24;
                int x = x0 - 15 + col;
                rl[i] = fx4{0.f, 0.f, 0.f, 0.f};
                if ((unsigned)x < WDIM)
                    rl[i] = *(const fx4*)&img[((size_t)x*HDIM + y0n)*CDIM + 4*v4];
            }
        }

        // ---- issue obs loads for epilogue rounds 0..3 (cover = main loop) --
        unsigned baseT[4];
#pragma unroll
        for (int k = 0; k < 4; ++k) baseT[k] = baseNoY[k] + (unsigned)(Y*CDIM);
        fx4 obA[4][4], obB[4][4];
#pragma unroll
        for (int s = 0; s < 4; ++s)
#pragma unroll
            for (int k = 0; k < 4; ++k)
                obA[s][k] = __builtin_nontemporal_load(
                    (const fx4*)&obs[baseT[k] + (unsigned)s*8*HDIM*CDIM]);

        // ---- main loop: pure-LDS C reads + global A (depth-2x2 prefetch) ---
        floatx16 acc[8] = {};
        const int KT = (Y + 497) & 63;       // slot(n,j) = (KT + n + j) & 63
        const __bf16* sIc = sim + c*TE + q*8;

        bf16x8 Aa0 = *(const bf16x8*)(gA);
        bf16x8 Aa1 = *(const bf16x8*)(gA + 1024);
        bf16x8 Ab0 = *(const bf16x8*)(gA + 2048);
        bf16x8 Ab1 = *(const bf16x8*)(gA + 3072);
#pragma unroll 1
        for (int jj = 0; jj < 32; jj += 2) {
            int jn2 = ((jj + 2) & 31) * 2048;
            bf16x8 Ac0 = *(const bf16x8*)(gA + jn2);
            bf16x8 Ac1 = *(const bf16x8*)(gA + jn2 + 1024);
            {   // body jj (uses Aa)
                int slot = (KT + n + jj) & 63;
                const __bf16* rowp = sIc + slot*TW;
                bf16x8 C[10];
#pragma unroll
                for (int rr = 0; rr < 10; ++rr)
                    C[rr] = *(const bf16x8*)(rowp + rr*8);
#pragma unroll
                for (int s = 0; s < 8; ++s) {
                    acc[s] = __builtin_amdgcn_mfma_f32_32x32x16_bf16(Aa0, C[s],   acc[s], 0, 0, 0);
                    acc[s] = __builtin_amdgcn_mfma_f32_32x32x16_bf16(Aa1, C[s+2], acc[s], 0, 0, 0);
                }
            }
            int jn3 = ((jj + 3) & 31) * 2048;
            bf16x8 Ad0 = *(const bf16x8*)(gA + jn3);
            bf16x8 Ad1 = *(const bf16x8*)(gA + jn3 + 1024);
            {   // body jj+1 (uses Ab)
                int slot = (KT + n + jj + 1) & 63;
                const __bf16* rowp = sIc + slot*TW;
                bf16x8 C[10];
#pragma unroll
                for (int rr = 0; rr < 10; ++rr)
                    C[rr] = *(const bf16x8*)(rowp + rr*8);
#pragma unroll
                for (int s = 0; s < 8; ++s) {
                    acc[s] = __builtin_amdgcn_mfma_f32_32x32x16_bf16(Ab0, C[s],   acc[s], 0, 0, 0);
                    acc[s] = __builtin_amdgcn_mfma_f32_32x32x16_bf16(Ab1, C[s+2], acc[s], 0, 0, 0);
                }
            }
            Aa0 = Ac0; Aa1 = Ac1; Ab0 = Ad0; Ab1 = Ad1;
        }

        // ---- issue obs loads for rounds 4..7 (cover = rounds 0..3) ----
#pragma unroll
        for (int s = 0; s < 4; ++s)
#pragma unroll
            for (int k = 0; k < 4; ++k)
                obB[s][k] = __builtin_nontemporal_load(
                    (const fx4*)&obs[baseT[k] + (unsigned)(s+4)*8*HDIM*CDIM]);

        // ---- epilogue: 8 transpose rounds, lgkm-only barriers ----
#pragma unroll
        for (int s = 0; s < 8; ++s) {
            barrier_lgkm();      // prior round's sOut reads complete
#pragma unroll
            for (int rr = 0; rr < 16; ++rr) {
                int b = (rr & 3) + 8*(rr >> 2) + 4*q;    // D row = batch
                sOut[(b*32 + n)*3 + c] = acc[s][rr];     // bank 3n+c
            }
            barrier_lgkm();      // sOut writes visible
#pragma unroll
            for (int k = 0; k < 4; ++k) {
                fx4 p = *(const fx4*)&sOut[4*(tid + 192*k)];
                __builtin_nontemporal_store(
                    p, (fx4*)&out[baseT[k] + (unsigned)s*8*HDIM*CDIM]);
                fx4 o = (s < 4) ? obA[s][k] : obB[s-4][k];
                fx4 d = o - p;
                ls += d[0]*d[0] + d[1]*d[1] + d[2]*d[2] + d[3]*d[3];
            }
        }
    }

#pragma unroll
    for (int m = 32; m >= 1; m >>= 1) ls += __shfl_xor(ls, m, 64);
    if (lane == 0) atomicAdd(out + NPRED, ls * (1.0f/(float)NPRED));
}

extern "C" void kernel_launch(void* const* d_in, const int* in_sizes, int n_in,
                              void* d_out, int out_size, void* d_ws, size_t ws_size,
                              hipStream_t stream) {
    const float* obs = (const float*)d_in[0];   // observed_images [32,512,512,3]
    const float* img = (const float*)d_in[1];   // estimated_image [512,512,3]
    const float* psf = (const float*)d_in[2];   // psfs [32,32,32,1,3]
    float* out = (float*)d_out;                 // pred (25165824) + loss (1)
    __bf16* psfA = (__bf16*)d_ws;               // 196608 B packed psf frags

    pack_psf<<<192, 64, 0, stream>>>(psf, psfA, out + NPRED);
    conv_mfma<<<256, 192, 0, stream>>>(obs, img, psfA, out);
}